// Round 12
// baseline (512.704 us; speedup 1.0000x reference)
//
#include <hip/hip_runtime.h>

typedef unsigned short ushort_t;
typedef __bf16 bf16x8 __attribute__((ext_vector_type(8)));
typedef float f32x4 __attribute__((ext_vector_type(4)));
typedef unsigned u32x4 __attribute__((ext_vector_type(4)));
typedef unsigned u32x2 __attribute__((ext_vector_type(2)));

// ---------- workspace layout (bytes) ----------
#define WS_FLAGS   0x0        // worker flags [16]x128B; P-flags @+2048; eg_done @+4096; feed_done @+4224
#define WS_CTX     0x14000    // ctx [32][1024] f32
#define WS_CTXT    0x34000    // ctx_T [1024][32] f32
#define WS_CTXRD   0x54000    // ctx_read [32][512] f32
#define WS_F1      0x64000    // F1r [512][32][4] f32 (feed+bias)
#define WS_F0      0xA4000    // F0r (bias only)
#define WS_EBF     0xE4000    // E_bf16 [2048][512]   (m' = t*32+b)
#define WS_WIH     0x2E4000   // Wih' bf16 [2048][512] (j' = 4d+g order)
#define WS_WHH     0x4E4000   // Whh' bf16 [2048][512]
#define WS_EG      0x26A4000  // Eg2 bf16 [64 t][512 d][32 b][4 g]  (8 MB)
#define WS_HH      0x2EA4000  // Hh bf16 [65 ts][32 b][512 d] write-once history
#define WS_P       0x38A4000  // P bf16 [64 t][32 b][512 n] write-once (2 MB)

__device__ __forceinline__ unsigned short f2bf(float f) {
  unsigned u = __builtin_bit_cast(unsigned, f);
  u = (u + 0x7FFFu + ((u >> 16) & 1u)) >> 16;
  return (unsigned short)u;
}
__device__ __forceinline__ float bfu2f(unsigned s) {
  return __builtin_bit_cast(float, s << 16);
}
__device__ __forceinline__ uint4 pack8(float4 a, float4 b) {
  uint4 o;
  o.x = (unsigned)f2bf(a.x) | ((unsigned)f2bf(a.y) << 16);
  o.y = (unsigned)f2bf(a.z) | ((unsigned)f2bf(a.w) << 16);
  o.z = (unsigned)f2bf(b.x) | ((unsigned)f2bf(b.y) << 16);
  o.w = (unsigned)f2bf(b.z) | ((unsigned)f2bf(b.w) << 16);
  return o;
}
__device__ __forceinline__ float sigm(float x) { return 1.0f / (1.0f + __expf(-x)); }
__device__ __forceinline__ float tanh_f(float x) {
  float a = fabsf(x);
  float t = __expf(-2.0f * a);
  float r = (1.0f - t) / (1.0f + t);
  return x < 0.0f ? -r : r;
}
__device__ __forceinline__ void gload_lds16(const void* g, void* l) {
  __builtin_amdgcn_global_load_lds((const __attribute__((address_space(1))) unsigned*)g,
                                   (__attribute__((address_space(3))) unsigned*)l, 16, 0, 0);
}
// sc1 = agent-coherent load: bypasses this XCD's (possibly stale) L1/L2, reads LLC.
__device__ __forceinline__ void gload_lds16_sc(const void* g, void* l) {
  __builtin_amdgcn_global_load_lds((const __attribute__((address_space(1))) unsigned*)g,
                                   (__attribute__((address_space(3))) unsigned*)l, 16, 0, 16);
}

// ---------- k_pre1: ctx/softmax (bid<32) + converts/gathers (bid 32..1575) + flag zero ----------
__global__ __launch_bounds__(256) void k_pre1(const float* __restrict__ xk,
                                              const float* __restrict__ xenc,
                                              const float* __restrict__ watt,
                                              float* __restrict__ ctx,
                                              float* __restrict__ ctxT,
                                              const float* __restrict__ W_ih,
                                              const float* __restrict__ W_hh,
                                              const float* __restrict__ h0f,
                                              const float* __restrict__ emb,
                                              const int* __restrict__ y_train,
                                              ushort_t* __restrict__ Wih,
                                              ushort_t* __restrict__ Whh,
                                              ushort_t* __restrict__ Hh,
                                              ushort_t* __restrict__ Ebf,
                                              int* __restrict__ flags) {
  const int bid = blockIdx.x, tid = threadIdx.x;

  if (bid < 32) {
    // ---- attention weights + ctx (step-independent) ----
    const int b = bid;
    __shared__ float part[256];
    __shared__ float attw[64];
    const int lq = tid >> 2, q = tid & 3;
    const float* row = xk + ((size_t)b * 64 + lq) * 512 + q * 128;
    const float* wa = watt + q * 128;
    float s = 0.0f;
    for (int i = 0; i < 128; i += 4) {
      float4 a = *(const float4*)(row + i);
      float4 w = *(const float4*)(wa + i);
      s += a.x * w.x + a.y * w.y + a.z * w.z + a.w * w.w;
    }
    part[tid] = s;
    __syncthreads();
    if (tid < 64) {
      float sc = part[tid * 4] + part[tid * 4 + 1] + part[tid * 4 + 2] + part[tid * 4 + 3];
      float m = sc;
      for (int off = 32; off; off >>= 1) m = fmaxf(m, __shfl_xor(m, off));
      float e = __expf(sc - m);
      float ssum = e;
      for (int off = 32; off; off >>= 1) ssum += __shfl_xor(ssum, off);
      attw[tid] = e / ssum;
    }
    __syncthreads();
    for (int v = tid; v < 1024; v += 256) {
      float a = 0.0f;
      for (int L = 0; L < 64; ++L) a += attw[L] * xenc[((size_t)b * 64 + L) * 1024 + v];
      ctx[b * 1024 + v] = a;
      ctxT[v * 32 + b] = a;
    }
    return;
  }
  if (bid == 1576) {
#pragma unroll
    for (int i = 0; i < 8; ++i) ((int*)flags)[i * 256 + tid] = 0;   // 8 KB: all flags+counters
    return;
  }

  // ---- converts / gathers (4 rows per 256-thread block) ----
  const int r = (bid - 32) * 4 + (tid >> 6);
  const int l = tid & 63;
  if (r < 2048) {
    const int j = (r & 3) * 512 + (r >> 2);
    const float* s = W_ih + (size_t)j * 1536 + l * 8;
    *(uint4*)(Wih + (size_t)r * 512 + l * 8) = pack8(*(const float4*)s, *(const float4*)(s + 4));
  } else if (r < 4096) {
    const int rr = r - 2048;
    const int j = (rr & 3) * 512 + (rr >> 2);
    const float* s = W_hh + (size_t)j * 512 + l * 8;
    *(uint4*)(Whh + (size_t)rr * 512 + l * 8) = pack8(*(const float4*)s, *(const float4*)(s + 4));
  } else if (r < 4128) {
    const int b = r - 4096;
    const float* s = h0f + b * 512 + l * 8;
    *(uint4*)(Hh + (size_t)b * 512 + l * 8) = pack8(*(const float4*)s, *(const float4*)(s + 4));
  } else {
    const int m = r - 4128;           // m' = t*32 + b
    const int t = m >> 5, b = m & 31;
    const int y = y_train[b * 64 + t];
    const float* s = emb + (size_t)y * 512 + l * 8;
    *(uint4*)(Ebf + (size_t)m * 512 + l * 8) = pack8(*(const float4*)s, *(const float4*)(s + 4));
  }
}

// ---------- mega-kernel: recurrence + full pre/post pipeline, 725 blocks ----------
// bid 0..15  : workers (proven path + one pre-loop gate on eg_done/feed_done)
// bid 16..23 : P-producers (crv load moved after first worker poll)
// bid 24..148: logits consumers (unchanged)
// bid 149..404: Eg GEMM blocks (operand-swapped; sc0sc1 publish; inc eg_done -> 256)
// bid 405..724: feed GEMV blocks (sc0sc1 publish; inc feed_done -> 320)
// Deadlock-free: spinners (149) < worst-case capacity (256 blocks); Eg/feed never spin.
__global__ __launch_bounds__(256, 1) void k_recur(ushort_t* __restrict__ Eg2,
                                                  float* __restrict__ F1,
                                                  float* __restrict__ F0,
                                                  const ushort_t* __restrict__ Whh,
                                                  const float* __restrict__ c_init,
                                                  ushort_t* __restrict__ Hh,
                                                  ushort_t* __restrict__ P,
                                                  int* __restrict__ flags,
                                                  const float* __restrict__ c2r,
                                                  float* __restrict__ ctx_read,
                                                  const float* __restrict__ Rw,
                                                  float* __restrict__ out,
                                                  const float* __restrict__ W_ih,
                                                  const float* __restrict__ bih,
                                                  const float* __restrict__ bhh,
                                                  const float* __restrict__ ctxT,
                                                  const ushort_t* __restrict__ Ebf,
                                                  const ushort_t* __restrict__ Wih16) {
  const int bid = blockIdx.x;
  const int tid = threadIdx.x;
  __shared__ __align__(16) char smem[37376];

  const int l = tid & 63, v = tid >> 6;
  const int q = l >> 4, ln = l & 15;

  if (bid >= 405) {
    // ---------------- feed GEMV (old k_feed), sc0sc1 publish + counter ----------------
    const int wg = bid - 405;
    const int b = tid & 31, sub = tid >> 5;
    if (wg < 256) {
      const int jp = wg * 8 + sub;          // j' row
      const int d = jp >> 2, g = jp & 3;
      const int j = g * 512 + d;            // original gate row
      const float* wr = W_ih + (size_t)j * 1536 + 512;
      float s = 0.0f;
      for (int vv = 0; vv < 1024; vv += 4) {
        float4 wv = *(const float4*)(wr + vv);
        s += ctxT[(vv + 0) * 32 + b] * wv.x + ctxT[(vv + 1) * 32 + b] * wv.y +
             ctxT[(vv + 2) * 32 + b] * wv.z + ctxT[(vv + 3) * 32 + b] * wv.w;
      }
      float bias = bih[j] + bhh[j];
      float v1 = s + bias;
      float* p1 = F1 + ((d * 32) + b) * 4 + g;
      float* p0 = F0 + ((d * 32) + b) * 4 + g;
      asm volatile("global_store_dword %0, %1, off sc0 sc1" :: "v"(p1), "v"(v1) : "memory");
      asm volatile("global_store_dword %0, %1, off sc0 sc1" :: "v"(p0), "v"(bias) : "memory");
    } else {
      const int n = (wg - 256) * 8 + sub;
      const float* cr = c2r + (size_t)512 * 512;  // ctx rows of ctx2read_w
      float s = 0.0f;
      for (int vv = 0; vv < 1024; ++vv) s += ctxT[vv * 32 + b] * cr[(size_t)vv * 512 + n];
      float* pc = ctx_read + b * 512 + n;
      asm volatile("global_store_dword %0, %1, off sc0 sc1" :: "v"(pc), "v"(s) : "memory");
    }
    asm volatile("s_waitcnt vmcnt(0)");
    __syncthreads();
    if (tid == 0)
      __hip_atomic_fetch_add(flags + 1056, 1, __ATOMIC_RELAXED, __HIP_MEMORY_SCOPE_AGENT);
    return;
  }

  if (bid >= 149) {
    // ---------------- Eg GEMM (operand-swapped: A=Wih16 j'-rows, B=Ebf m'-rows) ----------------
    ushort_t* As = (ushort_t*)smem;
    ushort_t* Bs = (ushort_t*)(smem + 16384);
    const int gb = bid - 149;
    const int m0 = (gb & 15) * 128;   // j' tile
    const int n0 = (gb >> 4) * 128;   // m' tile
    const int wv = tid >> 6;
    const int wm = wv >> 1, wn = wv & 1;
    const int lrow = l >> 3, lk = (l & 7) * 8;
    f32x4 acc[4][4] = {};

    for (int kt = 0; kt < 8; ++kt) {
      const int kbase = kt * 64;
#pragma unroll
      for (int i = 0; i < 4; ++i) {
        const int issue = wv * 4 + i;
        const int row = issue * 8 + lrow;
        gload_lds16(Wih16 + (size_t)(m0 + row) * 512 + kbase + lk, As + issue * 512);
        gload_lds16(Ebf + (size_t)(n0 + row) * 512 + kbase + lk, Bs + issue * 512);
      }
      __syncthreads();
#pragma unroll
      for (int half = 0; half < 2; ++half) {
        const int kb = half * 32 + (l >> 4) * 8;
        bf16x8 af[4], bfr[4];
#pragma unroll
        for (int mi = 0; mi < 4; ++mi)
          af[mi] = *(const bf16x8*)(As + (wm * 64 + mi * 16 + (l & 15)) * 64 + kb);
#pragma unroll
        for (int ni = 0; ni < 4; ++ni)
          bfr[ni] = *(const bf16x8*)(Bs + (wn * 64 + ni * 16 + (l & 15)) * 64 + kb);
#pragma unroll
        for (int mi = 0; mi < 4; ++mi)
#pragma unroll
          for (int ni = 0; ni < 4; ++ni)
            acc[mi][ni] = __builtin_amdgcn_mfma_f32_16x16x32_bf16(af[mi], bfr[ni], acc[mi][ni], 0, 0, 0);
      }
      __syncthreads();
    }

    // epilogue: lane holds 4 gates (r=g) of one d at one m' -> 8B sc0sc1 stores
#pragma unroll
    for (int mi = 0; mi < 4; ++mi) {
      const int jp = m0 + wm * 64 + mi * 16 + (l >> 4) * 4;  // j' base (mult of 4)
      const int d = jp >> 2;
#pragma unroll
      for (int ni = 0; ni < 4; ++ni) {
        const int mp = n0 + wn * 64 + ni * 16 + (l & 15);    // m' = t*32+b
        const int t = mp >> 5, b = mp & 31;
        u32x2 pv;
        pv.x = (unsigned)f2bf(acc[mi][ni][0]) | ((unsigned)f2bf(acc[mi][ni][1]) << 16);
        pv.y = (unsigned)f2bf(acc[mi][ni][2]) | ((unsigned)f2bf(acc[mi][ni][3]) << 16);
        ushort_t* dst = Eg2 + (size_t)t * 65536 + d * 128 + b * 4;
        asm volatile("global_store_dwordx2 %0, %1, off sc0 sc1" :: "v"(dst), "v"(pv) : "memory");
      }
    }
    asm volatile("s_waitcnt vmcnt(0)");
    __syncthreads();
    if (tid == 0)
      __hip_atomic_fetch_add(flags + 1024, 1, __ATOMIC_RELAXED, __HIP_MEMORY_SCOPE_AGENT);
    return;
  }

  if (bid >= 24) {
    // ---------------- logits path (unchanged) ----------------
    const int e = bid - 24;
    const int n0 = 256 * e;
    ushort_t* aL = (ushort_t*)smem;
    bf16x8 B[4][16];
#pragma unroll
    for (int nf = 0; nf < 4; ++nf)
#pragma unroll
      for (int kf = 0; kf < 16; ++kf) {
        bf16x8 tmp;
#pragma unroll
        for (int j = 0; j < 8; ++j)
          tmp[j] = (__bf16)Rw[(size_t)(kf * 32 + q * 8 + j) * 32000 + n0 + 64 * v + nf * 16 + ln];
        B[nf][kf] = tmp;
      }
    bool bail = false;
    for (int t = 0; t < 64; ++t) {
      if (!bail && tid < 8) {
        int spins = 0;
        while (__hip_atomic_load(flags + 512 + tid * 32, __ATOMIC_RELAXED, __HIP_MEMORY_SCOPE_AGENT) < t + 1) {
          __builtin_amdgcn_s_sleep(1);
          if (++spins > 2000000) { bail = true; break; }
        }
      }
      __syncthreads();
      const char* psrc = (const char*)P + (size_t)t * 32768;
#pragma unroll
      for (int rr = 0; rr < 8; ++rr) {
        const int R = v * 8 + rr;
        gload_lds16_sc(psrc + R * 1024 + ((16 * l) ^ ((R & 7) << 4)), (char*)aL + R * 1024);
      }
      __syncthreads();
      f32x4 acc[2][4] = {};
#pragma unroll
      for (int kf = 0; kf < 16; ++kf)
#pragma unroll
        for (int mf = 0; mf < 2; ++mf) {
          const int row = mf * 16 + ln;
          const int byteoff = (row * 1024 + kf * 64 + q * 16) ^ ((row & 7) << 4);
          bf16x8 a = *(const bf16x8*)((const char*)aL + byteoff);
#pragma unroll
          for (int nf = 0; nf < 4; ++nf)
            acc[mf][nf] = __builtin_amdgcn_mfma_f32_16x16x32_bf16(a, B[nf][kf], acc[mf][nf], 0, 0, 0);
        }
#pragma unroll
      for (int mf = 0; mf < 2; ++mf)
#pragma unroll
        for (int nf = 0; nf < 4; ++nf)
#pragma unroll
          for (int r = 0; r < 4; ++r) {
            const int brow = mf * 16 + q * 4 + r;
            out[(size_t)(brow * 64 + t) * 32000 + n0 + 64 * v + nf * 16 + ln] = acc[mf][nf][r];
          }
    }
    return;
  }

  if (bid >= 16) {
    // ---------------- P-producer path ----------------
    const int c = bid - 16;
    ushort_t* aL = (ushort_t*)smem;
    ushort_t* pOut = (ushort_t*)(smem + 32768);  // [32][72]
    const int myCol = 64 * c + 16 * v + ln;
    bf16x8 B[16];
#pragma unroll
    for (int kf = 0; kf < 16; ++kf) {
      bf16x8 tmp;
#pragma unroll
      for (int j = 0; j < 8; ++j)
        tmp[j] = (__bf16)c2r[(size_t)(kf * 32 + q * 8 + j) * 512 + myCol];
      B[kf] = tmp;
    }
    float crv[2][4];
    bool bail = false;
    for (int t = 0; t < 64; ++t) {
      if (!bail && tid < 16) {
        int spins = 0;
        while (__hip_atomic_load(flags + tid * 32, __ATOMIC_RELAXED, __HIP_MEMORY_SCOPE_AGENT) < t + 1) {
          __builtin_amdgcn_s_sleep(1);
          if (++spins > 2000000) { bail = true; break; }
        }
      }
      __syncthreads();
      if (t == 0) {
        // workers passed their feed gate (flag>=1) -> ctx_read final; safe to load now
#pragma unroll
        for (int mf = 0; mf < 2; ++mf)
#pragma unroll
          for (int r = 0; r < 4; ++r)
            crv[mf][r] = ctx_read[(mf * 16 + q * 4 + r) * 512 + myCol];
      }
      const char* hsrc = (const char*)Hh + (size_t)(t + 1) * 32768;
#pragma unroll
      for (int rr = 0; rr < 8; ++rr) {
        const int R = v * 8 + rr;
        gload_lds16_sc(hsrc + R * 1024 + ((16 * l) ^ ((R & 7) << 4)), (char*)aL + R * 1024);
      }
      __syncthreads();
      f32x4 acc[2] = {};
#pragma unroll
      for (int kf = 0; kf < 16; ++kf)
#pragma unroll
        for (int mf = 0; mf < 2; ++mf) {
          const int row = mf * 16 + ln;
          const int byteoff = (row * 1024 + kf * 64 + q * 16) ^ ((row & 7) << 4);
          bf16x8 a = *(const bf16x8*)((const char*)aL + byteoff);
          acc[mf] = __builtin_amdgcn_mfma_f32_16x16x32_bf16(a, B[kf], acc[mf], 0, 0, 0);
        }
#pragma unroll
      for (int mf = 0; mf < 2; ++mf)
#pragma unroll
        for (int r = 0; r < 4; ++r)
          pOut[(mf * 16 + q * 4 + r) * 72 + 16 * v + ln] = f2bf(tanh_f(acc[mf][r] + crv[mf][r]));
      __syncthreads();
      {
        const int b = tid >> 3, ch = tid & 7;
        u32x4 pv = *(const u32x4*)(pOut + b * 72 + ch * 8);
        char* pp = (char*)P + (size_t)t * 32768 + b * 1024 + 128 * c + ch * 16;
        asm volatile("global_store_dwordx4 %0, %1, off sc0 sc1" :: "v"(pp), "v"(pv) : "memory");
      }
      __syncthreads();   // publish drained (vmcnt0 before barrier)
      if (tid == 0)
        __hip_atomic_store(flags + 512 + c * 32, t + 1, __ATOMIC_RELAXED, __HIP_MEMORY_SCOPE_AGENT);
    }
    return;
  }

  // ---------------- worker path (proven; + pre-loop gate) ----------------
  const int w = bid;
  const int mh = v >> 1, nh = v & 1;
  ushort_t* hL = (ushort_t*)smem;
  ushort_t* hOutL = (ushort_t*)(smem + 32768);  // [32][40]

  bf16x8 WA[4][16];
#pragma unroll
  for (int mt = 0; mt < 4; ++mt)
#pragma unroll
    for (int kt = 0; kt < 16; ++kt)
      WA[mt][kt] = *(const bf16x8*)(Whh + (size_t)(128 * w + 64 * mh + mt * 16 + ln) * 512 + kt * 32 + q * 8);

  // gate: wait for in-kernel Eg GEMM (256 blocks) and feed (320 blocks) to publish
  if (tid == 0) {
    int spins = 0;
    while (__hip_atomic_load(flags + 1024, __ATOMIC_RELAXED, __HIP_MEMORY_SCOPE_AGENT) < 256) {
      __builtin_amdgcn_s_sleep(2);
      if (++spins > 4000000) break;
    }
    spins = 0;
    while (__hip_atomic_load(flags + 1056, __ATOMIC_RELAXED, __HIP_MEMORY_SCOPE_AGENT) < 320) {
      __builtin_amdgcn_s_sleep(2);
      if (++spins > 4000000) break;
    }
  }
  __syncthreads();

  const int b = 16 * nh + ln;
  const int d0 = 32 * w + 16 * mh;
  float cst[4];
  float4 fv1[4], fv0[4];
  uint2 egc[4];
#pragma unroll
  for (int mt = 0; mt < 4; ++mt) {
    const int d = d0 + mt * 4 + q;
    cst[mt] = c_init[b * 512 + d];
    fv1[mt] = *(const float4*)(F1 + (d * 32 + b) * 4);
    fv0[mt] = *(const float4*)(F0 + (d * 32 + b) * 4);
    egc[mt] = *(const uint2*)(Eg2 + ((size_t)d * 32 + b) * 4);
  }

  bool bail = false;
  for (int t = 0; t < 64; ++t) {
    const char* hsrc = (const char*)Hh + (size_t)t * 32768;
#pragma unroll
    for (int rr = 0; rr < 8; ++rr) {
      const int R = v * 8 + rr;
      gload_lds16_sc(hsrc + R * 1024 + ((16 * l) ^ ((R & 7) << 4)), (char*)hL + R * 1024);
    }
    uint2 egn[4];
    const int tn = (t + 1) & 63;
#pragma unroll
    for (int mt = 0; mt < 4; ++mt)
      egn[mt] = *(const uint2*)(Eg2 + ((size_t)(tn * 512 + d0 + mt * 4 + q) * 32 + b) * 4);
    __syncthreads();

    f32x4 acc[4] = {};
#pragma unroll
    for (int kt = 0; kt < 16; ++kt) {
      const int byteoff = (b * 1024 + kt * 64 + q * 16) ^ ((b & 7) << 4);
      bf16x8 hv = *(const bf16x8*)((const char*)hL + byteoff);
#pragma unroll
      for (int mt = 0; mt < 4; ++mt)
        acc[mt] = __builtin_amdgcn_mfma_f32_16x16x32_bf16(WA[mt][kt], hv, acc[mt], 0, 0, 0);
    }

#pragma unroll
    for (int mt = 0; mt < 4; ++mt) {
      const float4 fv = (t == 0) ? fv0[mt] : fv1[mt];
      float gi = acc[mt][0] + bfu2f(egc[mt].x & 0xFFFFu) + fv.x;
      float gf = acc[mt][1] + bfu2f(egc[mt].x >> 16) + fv.y;
      float gg = acc[mt][2] + bfu2f(egc[mt].y & 0xFFFFu) + fv.z;
      float go = acc[mt][3] + bfu2f(egc[mt].y >> 16) + fv.w;
      float c = sigm(gf) * cst[mt] + sigm(gi) * tanh_f(gg);
      cst[mt] = c;
      hOutL[b * 40 + 16 * mh + mt * 4 + q] = f2bf(sigm(go) * tanh_f(c));
      egc[mt] = egn[mt];
    }
    __syncthreads();

    if (tid < 128) {
      const int b2 = tid >> 2, c16 = (tid & 3) * 8;
      const u32x4 val = *(const u32x4*)(hOutL + b2 * 40 + c16);
      ushort_t* hp = Hh + (size_t)(t + 1) * 16384 + b2 * 512 + 32 * w + c16;
      asm volatile("global_store_dwordx4 %0, %1, off sc0 sc1" :: "v"(hp), "v"(val) : "memory");
    }
    __syncthreads();                       // publish drained (vmcnt0 before barrier)

    if (tid == 0)
      __hip_atomic_store(flags + w * 32, t + 1, __ATOMIC_RELAXED, __HIP_MEMORY_SCOPE_AGENT);

    if (t < 63) {
      if (!bail && tid < 16) {
        int spins = 0;
        while (__hip_atomic_load(flags + tid * 32, __ATOMIC_RELAXED, __HIP_MEMORY_SCOPE_AGENT) < t + 1) {
          __builtin_amdgcn_s_sleep(1);
          if (++spins > 2000000) { bail = true; break; }
        }
      }
      __syncthreads();
    }
  }
}

// ---------- launcher ----------
extern "C" void kernel_launch(void* const* d_in, const int* in_sizes, int n_in,
                              void* d_out, int out_size, void* d_ws, size_t ws_size,
                              hipStream_t stream) {
  const float* x_enc   = (const float*)d_in[0];
  const float* x_enc_k = (const float*)d_in[1];
  const float* h0f     = (const float*)d_in[2];
  const float* c0f     = (const float*)d_in[3];
  const int*   y_train = (const int*)d_in[5];
  const float* emb     = (const float*)d_in[7];
  const float* W_ih    = (const float*)d_in[8];
  const float* W_hh    = (const float*)d_in[9];
  const float* b_ih    = (const float*)d_in[10];
  const float* b_hh    = (const float*)d_in[11];
  const float* w_att   = (const float*)d_in[14];
  const float* c2r     = (const float*)d_in[16];
  const float* Rw      = (const float*)d_in[17];
  float* out = (float*)d_out;
  char* ws = (char*)d_ws;

  int*      flags    = (int*)(ws + WS_FLAGS);
  float*    ctx      = (float*)(ws + WS_CTX);
  float*    ctxT     = (float*)(ws + WS_CTXT);
  float*    ctx_read = (float*)(ws + WS_CTXRD);
  float*    F1r      = (float*)(ws + WS_F1);
  float*    F0r      = (float*)(ws + WS_F0);
  ushort_t* Ebf      = (ushort_t*)(ws + WS_EBF);
  ushort_t* Wih      = (ushort_t*)(ws + WS_WIH);
  ushort_t* Whh      = (ushort_t*)(ws + WS_WHH);
  ushort_t* Eg2      = (ushort_t*)(ws + WS_EG);
  ushort_t* Hh       = (ushort_t*)(ws + WS_HH);
  ushort_t* P        = (ushort_t*)(ws + WS_P);

  k_pre1<<<1577, 256, 0, stream>>>(x_enc_k, x_enc, w_att, ctx, ctxT,
                                   W_ih, W_hh, h0f, emb, y_train,
                                   Wih, Whh, Hh, Ebf, flags);
  k_recur<<<725, 256, 0, stream>>>(Eg2, F1r, F0r, Whh, c0f, Hh, P, flags,
                                   c2r, ctx_read, Rw, out,
                                   W_ih, b_ih, b_hh, ctxT, Ebf, Wih);
  (void)in_sizes; (void)n_in; (void)out_size; (void)ws_size;
}

// Round 13
// 336.238 us; speedup vs baseline: 1.5248x; 1.5248x over previous
//
#include <hip/hip_runtime.h>

typedef unsigned short ushort_t;
typedef __bf16 bf16x8 __attribute__((ext_vector_type(8)));
typedef float f32x4 __attribute__((ext_vector_type(4)));
typedef unsigned u32x4 __attribute__((ext_vector_type(4)));

// ---------- workspace layout (bytes) ----------
#define WS_FLAGS   0x0        // worker flags [16]x128B; P-flags @+2048; 8KB zeroed by k_pre1
#define WS_CTX     0x14000    // ctx [32][1024] f32
#define WS_CTXT    0x34000    // ctx_T [1024][32] f32
#define WS_CTXRD   0x54000    // ctx_read [32][512] f32
#define WS_F1      0x64000    // F1r [512][32][4] f32 (feed+bias)
#define WS_F0      0xA4000    // F0r (bias only)
#define WS_EBF     0xE4000    // E_bf16 [2048][512]   (m' = t*32+b)
#define WS_WIH     0x2E4000   // Wih' bf16 [2048][512] (j' = 4d+g order)
#define WS_WHH     0x4E4000   // Whh' bf16 [2048][512]
#define WS_EG      0x26A4000  // Eg2 bf16 [64 t][512 d][32 b][4 g]  (8 MB)
#define WS_HH      0x2EA4000  // Hh bf16 [65 ts][32 b][512 d] write-once history
#define WS_P       0x38A4000  // P bf16 [64 t][32 b][512 n] write-once (2 MB)

__device__ __forceinline__ unsigned short f2bf(float f) {
  unsigned u = __builtin_bit_cast(unsigned, f);
  u = (u + 0x7FFFu + ((u >> 16) & 1u)) >> 16;
  return (unsigned short)u;
}
__device__ __forceinline__ float bfu2f(unsigned s) {
  return __builtin_bit_cast(float, s << 16);
}
__device__ __forceinline__ uint4 pack8(float4 a, float4 b) {
  uint4 o;
  o.x = (unsigned)f2bf(a.x) | ((unsigned)f2bf(a.y) << 16);
  o.y = (unsigned)f2bf(a.z) | ((unsigned)f2bf(a.w) << 16);
  o.z = (unsigned)f2bf(b.x) | ((unsigned)f2bf(b.y) << 16);
  o.w = (unsigned)f2bf(b.z) | ((unsigned)f2bf(b.w) << 16);
  return o;
}
__device__ __forceinline__ float sigm(float x) { return 1.0f / (1.0f + __expf(-x)); }
__device__ __forceinline__ float tanh_f(float x) {
  float a = fabsf(x);
  float t = __expf(-2.0f * a);
  float r = (1.0f - t) / (1.0f + t);
  return x < 0.0f ? -r : r;
}
__device__ __forceinline__ void gload_lds16(const void* g, void* l) {
  __builtin_amdgcn_global_load_lds((const __attribute__((address_space(1))) unsigned*)g,
                                   (__attribute__((address_space(3))) unsigned*)l, 16, 0, 0);
}
// sc1 = agent-coherent load: bypasses this XCD's (possibly stale) L1/L2, reads LLC.
__device__ __forceinline__ void gload_lds16_sc(const void* g, void* l) {
  __builtin_amdgcn_global_load_lds((const __attribute__((address_space(1))) unsigned*)g,
                                   (__attribute__((address_space(3))) unsigned*)l, 16, 0, 16);
}

// ---------- k_pre1: ctx/softmax (bid<32) + converts/gathers (bid 32..1575) + flag zero ----------
__global__ __launch_bounds__(256) void k_pre1(const float* __restrict__ xk,
                                              const float* __restrict__ xenc,
                                              const float* __restrict__ watt,
                                              float* __restrict__ ctx,
                                              float* __restrict__ ctxT,
                                              const float* __restrict__ W_ih,
                                              const float* __restrict__ W_hh,
                                              const float* __restrict__ h0f,
                                              const float* __restrict__ emb,
                                              const int* __restrict__ y_train,
                                              ushort_t* __restrict__ Wih,
                                              ushort_t* __restrict__ Whh,
                                              ushort_t* __restrict__ Hh,
                                              ushort_t* __restrict__ Ebf,
                                              int* __restrict__ flags) {
  const int bid = blockIdx.x, tid = threadIdx.x;

  if (bid < 32) {
    // ---- attention weights + ctx (step-independent) ----
    const int b = bid;
    __shared__ float part[256];
    __shared__ float attw[64];
    const int lq = tid >> 2, q = tid & 3;
    const float* row = xk + ((size_t)b * 64 + lq) * 512 + q * 128;
    const float* wa = watt + q * 128;
    float s = 0.0f;
    for (int i = 0; i < 128; i += 4) {
      float4 a = *(const float4*)(row + i);
      float4 w = *(const float4*)(wa + i);
      s += a.x * w.x + a.y * w.y + a.z * w.z + a.w * w.w;
    }
    part[tid] = s;
    __syncthreads();
    if (tid < 64) {
      float sc = part[tid * 4] + part[tid * 4 + 1] + part[tid * 4 + 2] + part[tid * 4 + 3];
      float m = sc;
      for (int off = 32; off; off >>= 1) m = fmaxf(m, __shfl_xor(m, off));
      float e = __expf(sc - m);
      float ssum = e;
      for (int off = 32; off; off >>= 1) ssum += __shfl_xor(ssum, off);
      attw[tid] = e / ssum;
    }
    __syncthreads();
    // ctx apply: float4 over v, 2 independent partial accumulators (ILP)
    const int v0 = tid * 4;
    float4 a0 = {0.f, 0.f, 0.f, 0.f}, a1 = {0.f, 0.f, 0.f, 0.f};
#pragma unroll 8
    for (int L = 0; L < 64; L += 2) {
      const float w0 = attw[L], w1 = attw[L + 1];
      float4 x0 = *(const float4*)(xenc + ((size_t)b * 64 + L) * 1024 + v0);
      float4 x1 = *(const float4*)(xenc + ((size_t)b * 64 + L + 1) * 1024 + v0);
      a0.x += w0 * x0.x; a0.y += w0 * x0.y; a0.z += w0 * x0.z; a0.w += w0 * x0.w;
      a1.x += w1 * x1.x; a1.y += w1 * x1.y; a1.z += w1 * x1.z; a1.w += w1 * x1.w;
    }
    float4 a;
    a.x = a0.x + a1.x; a.y = a0.y + a1.y; a.z = a0.z + a1.z; a.w = a0.w + a1.w;
    *(float4*)(ctx + b * 1024 + v0) = a;
    ctxT[(v0 + 0) * 32 + b] = a.x;
    ctxT[(v0 + 1) * 32 + b] = a.y;
    ctxT[(v0 + 2) * 32 + b] = a.z;
    ctxT[(v0 + 3) * 32 + b] = a.w;
    return;
  }
  if (bid == 1576) {
#pragma unroll
    for (int i = 0; i < 8; ++i) ((int*)flags)[i * 256 + tid] = 0;   // 8 KB: all flags+counters
    return;
  }

  // ---- converts / gathers (4 rows per 256-thread block) ----
  const int r = (bid - 32) * 4 + (tid >> 6);
  const int l = tid & 63;
  if (r < 2048) {
    const int j = (r & 3) * 512 + (r >> 2);
    const float* s = W_ih + (size_t)j * 1536 + l * 8;
    *(uint4*)(Wih + (size_t)r * 512 + l * 8) = pack8(*(const float4*)s, *(const float4*)(s + 4));
  } else if (r < 4096) {
    const int rr = r - 2048;
    const int j = (rr & 3) * 512 + (rr >> 2);
    const float* s = W_hh + (size_t)j * 512 + l * 8;
    *(uint4*)(Whh + (size_t)rr * 512 + l * 8) = pack8(*(const float4*)s, *(const float4*)(s + 4));
  } else if (r < 4128) {
    const int b = r - 4096;
    const float* s = h0f + b * 512 + l * 8;
    *(uint4*)(Hh + (size_t)b * 512 + l * 8) = pack8(*(const float4*)s, *(const float4*)(s + 4));
  } else {
    const int m = r - 4128;           // m' = t*32 + b
    const int t = m >> 5, b = m & 31;
    const int y = y_train[b * 64 + t];
    const float* s = emb + (size_t)y * 512 + l * 8;
    *(uint4*)(Ebf + (size_t)m * 512 + l * 8) = pack8(*(const float4*)s, *(const float4*)(s + 4));
  }
}

// ---------- k_pre2: feed GEMV (bid<320) + Eg GEMM (bid 320..575) ----------
__global__ __launch_bounds__(256) void k_pre2(const float* __restrict__ ctxT,
                                              const float* __restrict__ W_ih,
                                              const float* __restrict__ bih,
                                              const float* __restrict__ bhh,
                                              const float* __restrict__ c2r,
                                              float* __restrict__ F1r,
                                              float* __restrict__ F0r,
                                              float* __restrict__ ctx_read,
                                              const ushort_t* __restrict__ A,
                                              const ushort_t* __restrict__ Bt,
                                              ushort_t* __restrict__ Cp) {
  const int bid = blockIdx.x, tid = threadIdx.x;
  __shared__ __align__(16) char smem[32768];

  if (bid < 320) {
    // ---- feed term + ctx_read (latency-optimized: independent partials) ----
    const int wg = bid;
    const int b = tid & 31, sub = tid >> 5;
    if (wg < 256) {
      const int jp = wg * 8 + sub;          // j' row
      const int d = jp >> 2, g = jp & 3;
      const int j = g * 512 + d;            // original gate row
      const float* wr = W_ih + (size_t)j * 1536 + 512;
      float s0 = 0.f, s1 = 0.f, s2 = 0.f, s3 = 0.f;
      for (int v = 0; v < 1024; v += 16) {
        float4 w0 = *(const float4*)(wr + v);
        float4 w1 = *(const float4*)(wr + v + 4);
        float4 w2 = *(const float4*)(wr + v + 8);
        float4 w3 = *(const float4*)(wr + v + 12);
        s0 += ctxT[(v + 0) * 32 + b] * w0.x + ctxT[(v + 1) * 32 + b] * w0.y +
              ctxT[(v + 2) * 32 + b] * w0.z + ctxT[(v + 3) * 32 + b] * w0.w;
        s1 += ctxT[(v + 4) * 32 + b] * w1.x + ctxT[(v + 5) * 32 + b] * w1.y +
              ctxT[(v + 6) * 32 + b] * w1.z + ctxT[(v + 7) * 32 + b] * w1.w;
        s2 += ctxT[(v + 8) * 32 + b] * w2.x + ctxT[(v + 9) * 32 + b] * w2.y +
              ctxT[(v + 10) * 32 + b] * w2.z + ctxT[(v + 11) * 32 + b] * w2.w;
        s3 += ctxT[(v + 12) * 32 + b] * w3.x + ctxT[(v + 13) * 32 + b] * w3.y +
              ctxT[(v + 14) * 32 + b] * w3.z + ctxT[(v + 15) * 32 + b] * w3.w;
      }
      float s = (s0 + s1) + (s2 + s3);
      float bias = bih[j] + bhh[j];
      F1r[((d * 32) + b) * 4 + g] = s + bias;
      F0r[((d * 32) + b) * 4 + g] = bias;
    } else {
      const int n = (wg - 256) * 8 + sub;
      const float* cr = c2r + (size_t)512 * 512;  // ctx rows of ctx2read_w
      float s0 = 0.f, s1 = 0.f, s2 = 0.f, s3 = 0.f;
      for (int v = 0; v < 1024; v += 8) {
        s0 += ctxT[(v + 0) * 32 + b] * cr[(size_t)(v + 0) * 512 + n] +
              ctxT[(v + 1) * 32 + b] * cr[(size_t)(v + 1) * 512 + n];
        s1 += ctxT[(v + 2) * 32 + b] * cr[(size_t)(v + 2) * 512 + n] +
              ctxT[(v + 3) * 32 + b] * cr[(size_t)(v + 3) * 512 + n];
        s2 += ctxT[(v + 4) * 32 + b] * cr[(size_t)(v + 4) * 512 + n] +
              ctxT[(v + 5) * 32 + b] * cr[(size_t)(v + 5) * 512 + n];
        s3 += ctxT[(v + 6) * 32 + b] * cr[(size_t)(v + 6) * 512 + n] +
              ctxT[(v + 7) * 32 + b] * cr[(size_t)(v + 7) * 512 + n];
      }
      ctx_read[b * 512 + n] = (s0 + s1) + (s2 + s3);
    }
    return;
  }

  // ---- Eg GEMM (old k_gemm<2>): C = Ebf @ Wih^T -> gate layout [t][d][b][g] ----
  ushort_t* As = (ushort_t*)smem;
  ushort_t* Bs = (ushort_t*)(smem + 16384);
  const int gb = bid - 320;
  const int m0 = (gb & 15) * 128, n0 = (gb >> 4) * 128;
  const int l = tid & 63, wv = tid >> 6;
  const int wm = wv >> 1, wn = wv & 1;
  const int lrow = l >> 3, lk = (l & 7) * 8;
  f32x4 acc[4][4] = {};

  for (int kt = 0; kt < 8; ++kt) {
    const int kbase = kt * 64;
#pragma unroll
    for (int i = 0; i < 4; ++i) {
      const int issue = wv * 4 + i;
      const int row = issue * 8 + lrow;
      gload_lds16(A + (size_t)(m0 + row) * 512 + kbase + lk, As + issue * 512);
      gload_lds16(Bt + (size_t)(n0 + row) * 512 + kbase + lk, Bs + issue * 512);
    }
    __syncthreads();
#pragma unroll
    for (int half = 0; half < 2; ++half) {
      const int kb = half * 32 + (l >> 4) * 8;
      bf16x8 af[4], bfr[4];
#pragma unroll
      for (int mi = 0; mi < 4; ++mi)
        af[mi] = *(const bf16x8*)(As + (wm * 64 + mi * 16 + (l & 15)) * 64 + kb);
#pragma unroll
      for (int ni = 0; ni < 4; ++ni)
        bfr[ni] = *(const bf16x8*)(Bs + (wn * 64 + ni * 16 + (l & 15)) * 64 + kb);
#pragma unroll
      for (int mi = 0; mi < 4; ++mi)
#pragma unroll
        for (int ni = 0; ni < 4; ++ni)
          acc[mi][ni] = __builtin_amdgcn_mfma_f32_16x16x32_bf16(af[mi], bfr[ni], acc[mi][ni], 0, 0, 0);
    }
    __syncthreads();
  }

#pragma unroll
  for (int mi = 0; mi < 4; ++mi) {
    const int row = m0 + wm * 64 + mi * 16 + (l >> 4) * 4;
#pragma unroll
    for (int ni = 0; ni < 4; ++ni) {
      const int col = n0 + wn * 64 + ni * 16 + (l & 15);
      const int d = col >> 2, g = col & 3;
#pragma unroll
      for (int r = 0; r < 4; ++r) {
        const int rr = row + r;                   // m' = t*32 + b
        const int t = rr >> 5, b = rr & 31;
        Cp[((size_t)(t * 512 + d) * 32 + b) * 4 + g] = f2bf(acc[mi][ni][r]);
      }
    }
  }
}

// ---------- recurrence + pipelined tail (P + logits), 149 co-resident blocks ----------
// bid 0..15  : workers (proven path; flag set EVERY step, final value 64)
// bid 16..23 : P-producers; bid 24..148: logits consumers.
__global__ __launch_bounds__(256, 1) void k_recur(const ushort_t* __restrict__ Eg2,
                                                  const float* __restrict__ F1,
                                                  const float* __restrict__ F0,
                                                  const ushort_t* __restrict__ Whh,
                                                  const float* __restrict__ c_init,
                                                  ushort_t* __restrict__ Hh,
                                                  ushort_t* __restrict__ P,
                                                  int* __restrict__ flags,
                                                  const float* __restrict__ c2r,
                                                  const float* __restrict__ ctx_read,
                                                  const float* __restrict__ Rw,
                                                  float* __restrict__ out) {
  const int bid = blockIdx.x;
  const int tid = threadIdx.x;
  __shared__ __align__(16) char smem[37376];   // 32K stage + bounce (32x40 / 32x72)

  const int l = tid & 63, v = tid >> 6;
  const int q = l >> 4, ln = l & 15;

  if (bid >= 24) {
    // ---------------- logits path ----------------
    const int e = bid - 24;
    const int n0 = 256 * e;
    ushort_t* aL = (ushort_t*)smem;
    bf16x8 B[4][16];
#pragma unroll
    for (int nf = 0; nf < 4; ++nf)
#pragma unroll
      for (int kf = 0; kf < 16; ++kf) {
        bf16x8 tmp;
#pragma unroll
        for (int j = 0; j < 8; ++j)
          tmp[j] = (__bf16)Rw[(size_t)(kf * 32 + q * 8 + j) * 32000 + n0 + 64 * v + nf * 16 + ln];
        B[nf][kf] = tmp;
      }
    bool bail = false;
    for (int t = 0; t < 64; ++t) {
      if (!bail && tid < 8) {
        int spins = 0;
        while (__hip_atomic_load(flags + 512 + tid * 32, __ATOMIC_RELAXED, __HIP_MEMORY_SCOPE_AGENT) < t + 1) {
          __builtin_amdgcn_s_sleep(1);
          if (++spins > 2000000) { bail = true; break; }
        }
      }
      __syncthreads();
      const char* psrc = (const char*)P + (size_t)t * 32768;
#pragma unroll
      for (int rr = 0; rr < 8; ++rr) {
        const int R = v * 8 + rr;
        gload_lds16_sc(psrc + R * 1024 + ((16 * l) ^ ((R & 7) << 4)), (char*)aL + R * 1024);
      }
      __syncthreads();
      f32x4 acc[2][4] = {};
#pragma unroll
      for (int kf = 0; kf < 16; ++kf)
#pragma unroll
        for (int mf = 0; mf < 2; ++mf) {
          const int row = mf * 16 + ln;
          const int byteoff = (row * 1024 + kf * 64 + q * 16) ^ ((row & 7) << 4);
          bf16x8 a = *(const bf16x8*)((const char*)aL + byteoff);
#pragma unroll
          for (int nf = 0; nf < 4; ++nf)
            acc[mf][nf] = __builtin_amdgcn_mfma_f32_16x16x32_bf16(a, B[nf][kf], acc[mf][nf], 0, 0, 0);
        }
#pragma unroll
      for (int mf = 0; mf < 2; ++mf)
#pragma unroll
        for (int nf = 0; nf < 4; ++nf)
#pragma unroll
          for (int r = 0; r < 4; ++r) {
            const int brow = mf * 16 + q * 4 + r;
            out[(size_t)(brow * 64 + t) * 32000 + n0 + 64 * v + nf * 16 + ln] = acc[mf][nf][r];
          }
    }
    return;
  }

  if (bid >= 16) {
    // ---------------- P-producer path ----------------
    const int c = bid - 16;
    ushort_t* aL = (ushort_t*)smem;
    ushort_t* pOut = (ushort_t*)(smem + 32768);  // [32][72]
    const int myCol = 64 * c + 16 * v + ln;
    bf16x8 B[16];
#pragma unroll
    for (int kf = 0; kf < 16; ++kf) {
      bf16x8 tmp;
#pragma unroll
      for (int j = 0; j < 8; ++j)
        tmp[j] = (__bf16)c2r[(size_t)(kf * 32 + q * 8 + j) * 512 + myCol];
      B[kf] = tmp;
    }
    float crv[2][4];
#pragma unroll
    for (int mf = 0; mf < 2; ++mf)
#pragma unroll
      for (int r = 0; r < 4; ++r)
        crv[mf][r] = ctx_read[(mf * 16 + q * 4 + r) * 512 + myCol];
    bool bail = false;
    for (int t = 0; t < 64; ++t) {
      if (!bail && tid < 16) {
        int spins = 0;
        while (__hip_atomic_load(flags + tid * 32, __ATOMIC_RELAXED, __HIP_MEMORY_SCOPE_AGENT) < t + 1) {
          __builtin_amdgcn_s_sleep(1);
          if (++spins > 2000000) { bail = true; break; }
        }
      }
      __syncthreads();
      const char* hsrc = (const char*)Hh + (size_t)(t + 1) * 32768;
#pragma unroll
      for (int rr = 0; rr < 8; ++rr) {
        const int R = v * 8 + rr;
        gload_lds16_sc(hsrc + R * 1024 + ((16 * l) ^ ((R & 7) << 4)), (char*)aL + R * 1024);
      }
      __syncthreads();
      f32x4 acc[2] = {};
#pragma unroll
      for (int kf = 0; kf < 16; ++kf)
#pragma unroll
        for (int mf = 0; mf < 2; ++mf) {
          const int row = mf * 16 + ln;
          const int byteoff = (row * 1024 + kf * 64 + q * 16) ^ ((row & 7) << 4);
          bf16x8 a = *(const bf16x8*)((const char*)aL + byteoff);
          acc[mf] = __builtin_amdgcn_mfma_f32_16x16x32_bf16(a, B[kf], acc[mf], 0, 0, 0);
        }
#pragma unroll
      for (int mf = 0; mf < 2; ++mf)
#pragma unroll
        for (int r = 0; r < 4; ++r)
          pOut[(mf * 16 + q * 4 + r) * 72 + 16 * v + ln] = f2bf(tanh_f(acc[mf][r] + crv[mf][r]));
      __syncthreads();
      {
        const int b = tid >> 3, ch = tid & 7;
        u32x4 pv = *(const u32x4*)(pOut + b * 72 + ch * 8);
        char* pp = (char*)P + (size_t)t * 32768 + b * 1024 + 128 * c + ch * 16;
        asm volatile("global_store_dwordx4 %0, %1, off sc0 sc1" :: "v"(pp), "v"(pv) : "memory");
      }
      __syncthreads();   // publish drained (vmcnt0 before barrier)
      if (tid == 0)
        __hip_atomic_store(flags + 512 + c * 32, t + 1, __ATOMIC_RELAXED, __HIP_MEMORY_SCOPE_AGENT);
    }
    return;
  }

  // ---------------- worker path (proven) ----------------
  const int w = bid;
  const int mh = v >> 1, nh = v & 1;
  ushort_t* hL = (ushort_t*)smem;
  ushort_t* hOutL = (ushort_t*)(smem + 32768);  // [32][40]

  bf16x8 WA[4][16];
#pragma unroll
  for (int mt = 0; mt < 4; ++mt)
#pragma unroll
    for (int kt = 0; kt < 16; ++kt)
      WA[mt][kt] = *(const bf16x8*)(Whh + (size_t)(128 * w + 64 * mh + mt * 16 + ln) * 512 + kt * 32 + q * 8);

  const int b = 16 * nh + ln;
  const int d0 = 32 * w + 16 * mh;
  float cst[4];
  float4 fv1[4], fv0[4];
  uint2 egc[4];
#pragma unroll
  for (int mt = 0; mt < 4; ++mt) {
    const int d = d0 + mt * 4 + q;
    cst[mt] = c_init[b * 512 + d];
    fv1[mt] = *(const float4*)(F1 + (d * 32 + b) * 4);
    fv0[mt] = *(const float4*)(F0 + (d * 32 + b) * 4);
    egc[mt] = *(const uint2*)(Eg2 + ((size_t)d * 32 + b) * 4);
  }

  bool bail = false;
  for (int t = 0; t < 64; ++t) {
    const char* hsrc = (const char*)Hh + (size_t)t * 32768;
#pragma unroll
    for (int rr = 0; rr < 8; ++rr) {
      const int R = v * 8 + rr;
      gload_lds16_sc(hsrc + R * 1024 + ((16 * l) ^ ((R & 7) << 4)), (char*)hL + R * 1024);
    }
    uint2 egn[4];
    const int tn = (t + 1) & 63;
#pragma unroll
    for (int mt = 0; mt < 4; ++mt)
      egn[mt] = *(const uint2*)(Eg2 + ((size_t)(tn * 512 + d0 + mt * 4 + q) * 32 + b) * 4);
    __syncthreads();

    f32x4 acc[4] = {};
#pragma unroll
    for (int kt = 0; kt < 16; ++kt) {
      const int byteoff = (b * 1024 + kt * 64 + q * 16) ^ ((b & 7) << 4);
      bf16x8 hv = *(const bf16x8*)((const char*)hL + byteoff);
#pragma unroll
      for (int mt = 0; mt < 4; ++mt)
        acc[mt] = __builtin_amdgcn_mfma_f32_16x16x32_bf16(WA[mt][kt], hv, acc[mt], 0, 0, 0);
    }

#pragma unroll
    for (int mt = 0; mt < 4; ++mt) {
      const float4 fv = (t == 0) ? fv0[mt] : fv1[mt];
      float gi = acc[mt][0] + bfu2f(egc[mt].x & 0xFFFFu) + fv.x;
      float gf = acc[mt][1] + bfu2f(egc[mt].x >> 16) + fv.y;
      float gg = acc[mt][2] + bfu2f(egc[mt].y & 0xFFFFu) + fv.z;
      float go = acc[mt][3] + bfu2f(egc[mt].y >> 16) + fv.w;
      float c = sigm(gf) * cst[mt] + sigm(gi) * tanh_f(gg);
      cst[mt] = c;
      hOutL[b * 40 + 16 * mh + mt * 4 + q] = f2bf(sigm(go) * tanh_f(c));
      egc[mt] = egn[mt];
    }
    __syncthreads();

    if (tid < 128) {
      const int b2 = tid >> 2, c16 = (tid & 3) * 8;
      const u32x4 val = *(const u32x4*)(hOutL + b2 * 40 + c16);
      ushort_t* hp = Hh + (size_t)(t + 1) * 16384 + b2 * 512 + 32 * w + c16;
      asm volatile("global_store_dwordx4 %0, %1, off sc0 sc1" :: "v"(hp), "v"(val) : "memory");
    }
    __syncthreads();                       // publish drained (vmcnt0 before barrier)

    if (tid == 0)
      __hip_atomic_store(flags + w * 32, t + 1, __ATOMIC_RELAXED, __HIP_MEMORY_SCOPE_AGENT);

    if (t < 63) {
      if (!bail && tid < 16) {
        int spins = 0;
        while (__hip_atomic_load(flags + tid * 32, __ATOMIC_RELAXED, __HIP_MEMORY_SCOPE_AGENT) < t + 1) {
          __builtin_amdgcn_s_sleep(1);
          if (++spins > 2000000) { bail = true; break; }
        }
      }
      __syncthreads();
    }
  }
}

// ---------- launcher ----------
extern "C" void kernel_launch(void* const* d_in, const int* in_sizes, int n_in,
                              void* d_out, int out_size, void* d_ws, size_t ws_size,
                              hipStream_t stream) {
  const float* x_enc   = (const float*)d_in[0];
  const float* x_enc_k = (const float*)d_in[1];
  const float* h0f     = (const float*)d_in[2];
  const float* c0f     = (const float*)d_in[3];
  const int*   y_train = (const int*)d_in[5];
  const float* emb     = (const float*)d_in[7];
  const float* W_ih    = (const float*)d_in[8];
  const float* W_hh    = (const float*)d_in[9];
  const float* b_ih    = (const float*)d_in[10];
  const float* b_hh    = (const float*)d_in[11];
  const float* w_att   = (const float*)d_in[14];
  const float* c2r     = (const float*)d_in[16];
  const float* Rw      = (const float*)d_in[17];
  float* out = (float*)d_out;
  char* ws = (char*)d_ws;

  int*      flags    = (int*)(ws + WS_FLAGS);
  float*    ctx      = (float*)(ws + WS_CTX);
  float*    ctxT     = (float*)(ws + WS_CTXT);
  float*    ctx_read = (float*)(ws + WS_CTXRD);
  float*    F1r      = (float*)(ws + WS_F1);
  float*    F0r      = (float*)(ws + WS_F0);
  ushort_t* Ebf      = (ushort_t*)(ws + WS_EBF);
  ushort_t* Wih      = (ushort_t*)(ws + WS_WIH);
  ushort_t* Whh      = (ushort_t*)(ws + WS_WHH);
  ushort_t* Eg2      = (ushort_t*)(ws + WS_EG);
  ushort_t* Hh       = (ushort_t*)(ws + WS_HH);
  ushort_t* P        = (ushort_t*)(ws + WS_P);

  k_pre1<<<1577, 256, 0, stream>>>(x_enc_k, x_enc, w_att, ctx, ctxT,
                                   W_ih, W_hh, h0f, emb, y_train,
                                   Wih, Whh, Hh, Ebf, flags);
  k_pre2<<<576, 256, 0, stream>>>(ctxT, W_ih, b_ih, b_hh, c2r, F1r, F0r, ctx_read,
                                  Ebf, Wih, Eg2);
  k_recur<<<149, 256, 0, stream>>>(Eg2, F1r, F0r, Whh, c0f, Hh, P, flags, c2r, ctx_read, Rw, out);
  (void)in_sizes; (void)n_in; (void)out_size; (void)ws_size;
}